// Round 20
// baseline (76.213 us; speedup 1.0000x reference)
//
#include <hip/hip_runtime.h>
#include <float.h>

// VectorQuantizer on MI355X — MFMA f16 screen + compacted np-f32 rescue.
// R20 = R18 geometry (best: 43.3us) + A-operand reuse + loss merged into main.
//
// R18 analysis: screen's embA stream = 8192 waves x 32KB = 256MB L2 (~7-15us),
// the largest single stream (HBM only ~26MB). R19 (2-tile pipeline) regressed
// via LDS 40KB -> occupancy 20%; reverted.
// R20: wave covers (pixel-group w&1 [32 px], code-quarter w>>1 [128 codes]):
// A-loads/wave halve (16 vs 32), MFMA count (32) and hv footprint (64 vals/lane)
// unchanged -> embA traffic 128MB. Screen values bit-identical to R18 (same
// fragments, same fmaf chain); per-pixel min merged over the 4 owning waves
// (fminf order-independent) -> identical thr -> identical candidates -> idx
// bit-identical. vq_loss folded in via last-block-done reduction (proven R19).
#pragma clang fp contract(off)

#define K_EMB   512
#define D_EMB   64
#define Q_ELEMS 4194304   // 64 * 64 * 32 * 32
#define NBLK    1024      // 64 pixels per block
#define W_SCR   0.5f      // rescue window, scaled (512x) — validated R13-R19
#define XROW    65        // xf row stride (odd -> bank-spread)
#define LCAP    1024      // candidate list capacity (avg ~77/block)

typedef _Float16 f16x8 __attribute__((ext_vector_type(8)));
typedef _Float16 f16x2 __attribute__((ext_vector_type(2)));
typedef float    f32x4 __attribute__((ext_vector_type(4)));

// numpy pairwise_sum order for n=64 contiguous f32, summing PRE-ROUNDED squares.
__device__ __forceinline__ float np_sumsq64(const float* v) {
    float r[8];
    #pragma unroll
    for (int j = 0; j < 8; ++j) r[j] = v[j] * v[j];
    #pragma unroll
    for (int i = 8; i < 64; i += 8) {
        #pragma unroll
        for (int j = 0; j < 8; ++j) {
            float s = v[i + j] * v[i + j];
            r[j] = r[j] + s;
        }
    }
    return ((r[0] + r[1]) + (r[2] + r[3])) + ((r[4] + r[5]) + (r[6] + r[7]));
}

// ---------------- kernel 1: t2, 512*t2, A-fragment table, zero done-counter ----
// embA slot g=(t*2+s)*64+l: lane l's A-frag for code tile t, k-step s:
// code=t*16+(l&15), dims d = s*32+(l>>4)*8 .. +8, values u=512e (pow2-exact).
__global__ __launch_bounds__(256) void vq_prep(const float* __restrict__ emb,
                                               float* __restrict__ t2,
                                               float* __restrict__ t2s512,
                                               f16x8* __restrict__ embA,
                                               unsigned int* __restrict__ done) {
    const int g = blockIdx.x * 256 + threadIdx.x;
    if (g == 0) *done = 0u;
    if (g < K_EMB) {
        const float* ep = emb + (g << 6);
        float s = np_sumsq64(ep);
        t2[g]     = s;
        t2s512[g] = 512.0f * s;
    }
    if (g < 4096) {
        const int t = g >> 7;
        const int s = (g >> 6) & 1;
        const int l = g & 63;
        const int code  = t * 16 + (l & 15);
        const int dbase = s * 32 + ((l >> 4) << 3);
        const float* ep = emb + (code << 6) + dbase;
        f16x8 a;
        #pragma unroll
        for (int i = 0; i < 8; ++i) a[i] = (_Float16)(512.0f * ep[i]);
        embA[g] = a;
    }
}

// ---------------- kernel 2: main VQ (wave: 32 pixels x 128 codes) -------------
__global__ __launch_bounds__(512) void vq_main(const float* __restrict__ x,
                                               const float* __restrict__ emb,
                                               const float* __restrict__ t2,
                                               const float* __restrict__ t2s512,
                                               const f16x8* __restrict__ embA,
                                               float* __restrict__ out_q,
                                               float* __restrict__ out_idx,
                                               float* __restrict__ partial,
                                               unsigned int* __restrict__ done,
                                               float* __restrict__ loss) {
    const int tid  = threadIdx.x;
    const int lane = tid & 63;
    const int wave = tid >> 6;                  // 0..7
    const int pg   = wave & 1;                  // pixel-group (32 pixels)
    const int cq   = wave >> 1;                 // code-quarter (8 MFMA tiles)
    const int p    = tid & 63;                  // stage/epilogue pixel role

    __shared__ float xf[64 * XROW];             // f32 x-tile, staged ONCE
    __shared__ float t1s[64];                   // np-exact t1 per pixel
    __shared__ float mwv[8][2][16];             // per-(wave, sub-tile, pixel) min
    __shared__ unsigned long long keys[64];     // (bits(dist)<<32)|k per pixel
    __shared__ int   list[LCAP];                // packed candidates p*512+k
    __shared__ int   lcnt;
    __shared__ float red[8];
    __shared__ int   lastf;

    // ---- stage: thread (p, oct = wave) loads 8 dims, coalesced per-d ----
    {
        const int np_ = blockIdx.x * 64 + p;
        const float* __restrict__ xs = x + (np_ >> 10) * 65536 + (np_ & 1023);
        #pragma unroll
        for (int j = 0; j < 8; ++j)
            xf[p * XROW + wave * 8 + j] = xs[(wave * 8 + j) * 1024];
        if (tid < 64) keys[tid] = 0xFFFFFFFFFFFFFFFFull;
        if (tid == 0) lcnt = 0;
    }
    __syncthreads();

    // ---- wave 0: t1 per pixel (np-exact, contiguous LDS row) ----
    if (wave == 0) t1s[lane] = np_sumsq64(&xf[lane * XROW]);
    // (consumed by rescue, after the post-pass2 barrier)

    // ---- B-fragments: this wave's 32 pixels = 2 sub-tiles of 16 ----
    const int bp0 = 32 * pg + (lane & 15);      // sub-tile 0 pixel row
    const int bp1 = bp0 + 16;                   // sub-tile 1 pixel row
    const int bg  = lane >> 4;                  // code-slice group
    f16x8 b00, b01, b10, b11;
    #pragma unroll
    for (int i = 0; i < 8; ++i) {
        b00[i] = (_Float16)xf[bp0 * XROW + 0 * 32 + bg * 8 + i];
        b01[i] = (_Float16)xf[bp0 * XROW + 1 * 32 + bg * 8 + i];
        b10[i] = (_Float16)xf[bp1 * XROW + 0 * 32 + bg * 8 + i];
        b11[i] = (_Float16)xf[bp1 * XROW + 1 * 32 + bg * 8 + i];
    }

    const f32x4 czero = {0.f, 0.f, 0.f, 0.f};
    const float4* __restrict__ t2s4 = (const float4*)t2s512;
    const int t0 = cq * 8;                      // this wave's 8 code tiles

    // ---- pass 1: screen 32 px x 128 codes; A loaded once per tile ----
    f16x2 hv0[16], hv1[16];                     // 32+32 screen values packed
    float m0 = FLT_MAX, m1 = FLT_MAX;
    #pragma unroll
    for (int tt = 0; tt < 8; ++tt) {
        const int t = t0 + tt;
        f16x8 a0 = embA[(t * 2 + 0) * 64 + lane];
        f16x8 a1 = embA[(t * 2 + 1) * 64 + lane];
        f32x4 c0 = __builtin_amdgcn_mfma_f32_16x16x32_f16(a0, b00, czero, 0, 0, 0);
        c0 = __builtin_amdgcn_mfma_f32_16x16x32_f16(a1, b01, c0, 0, 0, 0);
        f32x4 c1 = __builtin_amdgcn_mfma_f32_16x16x32_f16(a0, b10, czero, 0, 0, 0);
        c1 = __builtin_amdgcn_mfma_f32_16x16x32_f16(a1, b11, c1, 0, 0, 0);
        float4 tv = t2s4[t * 4 + bg];
        float s00 = fmaf(-2.f, c0[0], tv.x);
        float s01 = fmaf(-2.f, c0[1], tv.y);
        float s02 = fmaf(-2.f, c0[2], tv.z);
        float s03 = fmaf(-2.f, c0[3], tv.w);
        float s10 = fmaf(-2.f, c1[0], tv.x);
        float s11 = fmaf(-2.f, c1[1], tv.y);
        float s12 = fmaf(-2.f, c1[2], tv.z);
        float s13 = fmaf(-2.f, c1[3], tv.w);
        f16x2 q0, q1, q2, q3;
        q0[0] = (_Float16)s00; q0[1] = (_Float16)s01;
        q1[0] = (_Float16)s02; q1[1] = (_Float16)s03;
        q2[0] = (_Float16)s10; q2[1] = (_Float16)s11;
        q3[0] = (_Float16)s12; q3[1] = (_Float16)s13;
        hv0[tt * 2 + 0] = q0;  hv0[tt * 2 + 1] = q1;
        hv1[tt * 2 + 0] = q2;  hv1[tt * 2 + 1] = q3;
        m0 = fminf(m0, fminf(fminf(s00, s01), fminf(s02, s03)));
        m1 = fminf(m1, fminf(fminf(s10, s11), fminf(s12, s13)));
    }
    m0 = fminf(m0, __shfl_xor(m0, 16));
    m0 = fminf(m0, __shfl_xor(m0, 32));
    m1 = fminf(m1, __shfl_xor(m1, 16));
    m1 = fminf(m1, __shfl_xor(m1, 32));
    if (lane < 16) {
        mwv[wave][0][lane] = m0;
        mwv[wave][1][lane] = m1;
    }
    __syncthreads();                                            // B1

    // per-pixel threshold: min over the 4 waves owning this pixel-group
    const int li = lane & 15;
    const float thr0 = fminf(fminf(mwv[pg][0][li],     mwv[pg + 2][0][li]),
                             fminf(mwv[pg + 4][0][li], mwv[pg + 6][0][li])) + W_SCR;
    const float thr1 = fminf(fminf(mwv[pg][1][li],     mwv[pg + 2][1][li]),
                             fminf(mwv[pg + 4][1][li], mwv[pg + 6][1][li])) + W_SCR;

    // ---- pass 2: pure register scan, COLLECT candidates ----
    #pragma unroll
    for (int tt = 0; tt < 8; ++tt) {
        const int kb = (t0 + tt) * 16 + bg * 4;
        f16x2 q0 = hv0[tt * 2 + 0], q1 = hv0[tt * 2 + 1];
        f16x2 q2 = hv1[tt * 2 + 0], q3 = hv1[tt * 2 + 1];
        float s00 = (float)q0[0], s01 = (float)q0[1];
        float s02 = (float)q1[0], s03 = (float)q1[1];
        float s10 = (float)q2[0], s11 = (float)q2[1];
        float s12 = (float)q3[0], s13 = (float)q3[1];
        if (s00 < thr0) { int s = atomicAdd(&lcnt, 1); if (s < LCAP) list[s] = bp0 * 512 + kb + 0; }
        if (s01 < thr0) { int s = atomicAdd(&lcnt, 1); if (s < LCAP) list[s] = bp0 * 512 + kb + 1; }
        if (s02 < thr0) { int s = atomicAdd(&lcnt, 1); if (s < LCAP) list[s] = bp0 * 512 + kb + 2; }
        if (s03 < thr0) { int s = atomicAdd(&lcnt, 1); if (s < LCAP) list[s] = bp0 * 512 + kb + 3; }
        if (s10 < thr1) { int s = atomicAdd(&lcnt, 1); if (s < LCAP) list[s] = bp1 * 512 + kb + 0; }
        if (s11 < thr1) { int s = atomicAdd(&lcnt, 1); if (s < LCAP) list[s] = bp1 * 512 + kb + 1; }
        if (s12 < thr1) { int s = atomicAdd(&lcnt, 1); if (s < LCAP) list[s] = bp1 * 512 + kb + 2; }
        if (s13 < thr1) { int s = atomicAdd(&lcnt, 1); if (s < LCAP) list[s] = bp1 * 512 + kb + 3; }
    }
    __syncthreads();                                            // B2

    // ---- rescue: exact np-f32, one candidate per lane, operands from LDS ----
    const int ncand = min(lcnt, LCAP);
    for (int i = tid; i < ncand; i += 512) {
        const int v  = list[i];
        const int pp = v >> 9;
        const int k  = v & 511;
        const float* xp = &xf[pp * XROW];
        const float* __restrict__ ep = emb + (k << 6);
        float a = 0.f;
        #pragma unroll
        for (int d = 0; d < D_EMB; ++d) a = fmaf(xp[d], ep[d], a);
        float X = t1s[pp] + t2[k];
        float dnp = fmaf(-2.f, a, X);
        unsigned long long key =
            ((unsigned long long)__float_as_uint(dnp) << 32) | (unsigned)k;
        atomicMin(&keys[pp], key);
    }
    __syncthreads();                                            // B3

    // ---- epilogue: thread (p, oct = wave): 8 dims; loss partial ----
    float acc = 0.f;
    {
        const int n2 = blockIdx.x * 64 + p;
        const int kw = (int)(unsigned)(keys[p] & 0xFFFFFFFFull);
        float* __restrict__ qp = out_q + (n2 >> 10) * 65536 + (n2 & 1023);
        const float4* __restrict__ eq = (const float4*)(emb + (kw << 6) + wave * 8);
        #pragma unroll
        for (int j4 = 0; j4 < 2; ++j4) {
            float4 qv = eq[j4];
            const int d = wave * 8 + j4 * 4;
            float f0 = qv.x - xf[p * XROW + d + 0];
            float f1 = qv.y - xf[p * XROW + d + 1];
            float f2 = qv.z - xf[p * XROW + d + 2];
            float f3 = qv.w - xf[p * XROW + d + 3];
            acc = fmaf(f0, f0, acc);
            acc = fmaf(f1, f1, acc);
            acc = fmaf(f2, f2, acc);
            acc = fmaf(f3, f3, acc);
            qp[(d + 0) * 1024] = qv.x;
            qp[(d + 1) * 1024] = qv.y;
            qp[(d + 2) * 1024] = qv.z;
            qp[(d + 3) * 1024] = qv.w;
        }
        if (wave == 0) out_idx[n2] = (float)kw;
    }

    // ---- block loss partial ----
    #pragma unroll
    for (int off = 32; off > 0; off >>= 1) acc += __shfl_down(acc, off);
    if (lane == 0) red[wave] = acc;
    __syncthreads();
    if (tid == 0) {
        partial[blockIdx.x] = ((red[0] + red[1]) + (red[2] + red[3]))
                            + ((red[4] + red[5]) + (red[6] + red[7]));
        __threadfence();
        unsigned int old = atomicAdd(done, 1u);
        lastf = (old == NBLK - 1) ? 1 : 0;
    }
    __syncthreads();

    // ---- last block: deterministic loss finalize over 1024 partials ----
    if (lastf) {
        __threadfence();
        float a = __hip_atomic_load(&partial[tid], __ATOMIC_RELAXED,
                                    __HIP_MEMORY_SCOPE_AGENT);
        float b = __hip_atomic_load(&partial[tid + 512], __ATOMIC_RELAXED,
                                    __HIP_MEMORY_SCOPE_AGENT);
        float v = a + b;
        #pragma unroll
        for (int off = 32; off > 0; off >>= 1) v += __shfl_down(v, off);
        if (lane == 0) red[wave] = v;
        __syncthreads();
        if (tid == 0)
            loss[0] = 1.25f * (((red[0] + red[1]) + (red[2] + red[3]))
                             + ((red[4] + red[5]) + (red[6] + red[7]))) / (float)Q_ELEMS;
    }
}

extern "C" void kernel_launch(void* const* d_in, const int* in_sizes, int n_in,
                              void* d_out, int out_size, void* d_ws, size_t ws_size,
                              hipStream_t stream) {
    const float* x   = (const float*)d_in[0];   // [64,64,32,32] NCHW
    const float* emb = (const float*)d_in[1];   // [512,64]

    float* out_q    = (float*)d_out;                // [4194304]
    float* out_loss = (float*)d_out + Q_ELEMS;      // [1]
    float* out_idx  = (float*)d_out + Q_ELEMS + 1;  // [65536] as float

    float*        t2      = (float*)d_ws;                     // 512
    float*        t2s512  = t2 + K_EMB;                       // 512
    float*        partial = t2s512 + K_EMB;                   // 1024
    unsigned int* done    = (unsigned int*)(partial + 1024);  // 1
    f16x8*        embA    = (f16x8*)((float*)d_ws + 2560);    // 16B-aligned, 64KB

    vq_prep<<<16, 256, 0, stream>>>(emb, t2, t2s512, embA, done);
    vq_main<<<NBLK, 512, 0, stream>>>(x, emb, t2, t2s512, embA,
                                      out_q, out_idx, partial, done, out_loss);
}

// Round 21
// 43.700 us; speedup vs baseline: 1.7440x; 1.7440x over previous
//
#include <hip/hip_runtime.h>
#include <float.h>

// VectorQuantizer on MI355X — MFMA f16 screen (register-held) + compacted np-f32
// rescue, x in LDS, 8-wave blocks. EXACT RESTORE OF R18 (session best: 43.3us).
//
// R19 (2-tile pipeline: LDS 40KB, VGPR 108 -> occ 20%, 66us) and R20 (A-reuse:
// VGPR 72 crosses the 64-reg/8-wave tier, 2x bank conflicts -> 76us) both
// regressed by breaking R18's resource envelope (VGPR=64 exactly at tier edge,
// LDS 22.5KB). Lesson: at this problem size the plateau (43-48us across six
// structural variants) is latency/dispatch-structural; every "win" that adds
// register or LDS pressure loses more than it gains. Restoring the optimum.
#pragma clang fp contract(off)

#define K_EMB   512
#define D_EMB   64
#define Q_ELEMS 4194304   // 64 * 64 * 32 * 32
#define NBLK    1024      // 64 pixels per block
#define W_SCR   0.5f      // rescue window, scaled (512x) — validated R13-R20
#define XROW    65        // xf row stride (odd -> bank-spread)
#define LCAP    1024      // candidate list capacity (avg ~77/block)

typedef _Float16 f16x8 __attribute__((ext_vector_type(8)));
typedef _Float16 f16x2 __attribute__((ext_vector_type(2)));
typedef float    f32x4 __attribute__((ext_vector_type(4)));

// numpy pairwise_sum order for n=64 contiguous f32, summing PRE-ROUNDED squares.
__device__ __forceinline__ float np_sumsq64(const float* v) {
    float r[8];
    #pragma unroll
    for (int j = 0; j < 8; ++j) r[j] = v[j] * v[j];
    #pragma unroll
    for (int i = 8; i < 64; i += 8) {
        #pragma unroll
        for (int j = 0; j < 8; ++j) {
            float s = v[i + j] * v[i + j];
            r[j] = r[j] + s;
        }
    }
    return ((r[0] + r[1]) + (r[2] + r[3])) + ((r[4] + r[5]) + (r[6] + r[7]));
}

// ---------------- kernel 1: t2 (np-exact), 512-scaled t2, A-fragment table ----
// embA slot g=(t*2+s)*64+l: lane l's A-frag for code tile t, k-step s:
// code=t*16+(l&15), dims d = s*32+(l>>4)*8 .. +8, values u=512e (pow2-exact).
__global__ __launch_bounds__(256) void vq_prep(const float* __restrict__ emb,
                                               float* __restrict__ t2,
                                               float* __restrict__ t2s512,
                                               f16x8* __restrict__ embA) {
    const int g = blockIdx.x * 256 + threadIdx.x;
    if (g < K_EMB) {
        const float* ep = emb + (g << 6);
        float s = np_sumsq64(ep);
        t2[g]     = s;
        t2s512[g] = 512.0f * s;
    }
    if (g < 4096) {
        const int t = g >> 7;
        const int s = (g >> 6) & 1;
        const int l = g & 63;
        const int code  = t * 16 + (l & 15);
        const int dbase = s * 32 + ((l >> 4) << 3);
        const float* ep = emb + (code << 6) + dbase;
        f16x8 a;
        #pragma unroll
        for (int i = 0; i < 8; ++i) a[i] = (_Float16)(512.0f * ep[i]);
        embA[g] = a;
    }
}

// ---------------- kernel 2: main VQ (8 waves: pixel-tile x code-half) ---------
__global__ __launch_bounds__(512) void vq_main(const float* __restrict__ x,
                                               const float* __restrict__ emb,
                                               const float* __restrict__ t2,
                                               const float* __restrict__ t2s512,
                                               const f16x8* __restrict__ embA,
                                               float* __restrict__ out_q,
                                               float* __restrict__ out_idx,
                                               float* __restrict__ partial) {
    const int tid  = threadIdx.x;
    const int lane = tid & 63;
    const int wave = tid >> 6;                  // 0..7
    const int pt   = wave & 3;                  // pixel-tile (16 pixels)
    const int ch   = wave >> 2;                 // code-half (16 MFMA tiles)

    __shared__ float xf[64 * XROW];             // f32 x-tile, staged ONCE
    __shared__ float t1s[64];                   // np-exact t1 per pixel
    __shared__ float mwv[8][16];                // per-(wave, pixel-in-tile) min
    __shared__ unsigned long long keys[64];     // (bits(dist)<<32)|k per pixel
    __shared__ int   list[LCAP];                // packed candidates p*512+k
    __shared__ int   lcnt;
    __shared__ float red[8];

    // ---- stage: thread (p = tid&63, oct = wave) loads 8 dims, coalesced ----
    {
        const int p = tid & 63;
        const int np_ = blockIdx.x * 64 + p;
        const float* __restrict__ xs = x + (np_ >> 10) * 65536 + (np_ & 1023);
        #pragma unroll
        for (int j = 0; j < 8; ++j) {
            const int d = wave * 8 + j;
            xf[p * XROW + d] = xs[d * 1024];
        }
        if (tid < 64) keys[tid] = 0xFFFFFFFFFFFFFFFFull;
        if (tid == 0) lcnt = 0;
    }
    __syncthreads();

    // ---- wave 0: t1 per pixel (np-exact, contiguous LDS row) ----
    if (wave == 0) t1s[lane] = np_sumsq64(&xf[lane * XROW]);
    // (consumed by rescue, after the post-pass2 barrier)

    // ---- B-fragments for this wave's 16 pixels (RN f16 cvt from LDS f32) ----
    const int bp = 16 * pt + (lane & 15);       // pixel row
    const int bg = lane >> 4;                   // code-slice group
    f16x8 b0, b1;
    #pragma unroll
    for (int i = 0; i < 8; ++i) {
        b0[i] = (_Float16)xf[bp * XROW + 0 * 32 + bg * 8 + i];
        b1[i] = (_Float16)xf[bp * XROW + 1 * 32 + bg * 8 + i];
    }

    const f32x4 czero = {0.f, 0.f, 0.f, 0.f};
    const float4* __restrict__ t2s4 = (const float4*)t2s512;
    const int t0 = ch * 16;                     // this wave's 16 code tiles

    // ---- pass 1: screen all 256 codes; pack dists to f16 regs; track min ----
    f16x2 hv[32];                               // 64 screen values, packed
    float m = FLT_MAX;
    #pragma unroll
    for (int tt = 0; tt < 16; ++tt) {
        const int t = t0 + tt;
        f16x8 a0 = embA[(t * 2 + 0) * 64 + lane];
        f16x8 a1 = embA[(t * 2 + 1) * 64 + lane];
        f32x4 c = __builtin_amdgcn_mfma_f32_16x16x32_f16(a0, b0, czero, 0, 0, 0);
        c = __builtin_amdgcn_mfma_f32_16x16x32_f16(a1, b1, c, 0, 0, 0);
        float4 tv = t2s4[t * 4 + bg];
        float s0 = fmaf(-2.f, c[0], tv.x);
        float s1 = fmaf(-2.f, c[1], tv.y);
        float s2 = fmaf(-2.f, c[2], tv.z);
        float s3 = fmaf(-2.f, c[3], tv.w);
        f16x2 p01, p23;
        p01[0] = (_Float16)s0; p01[1] = (_Float16)s1;
        p23[0] = (_Float16)s2; p23[1] = (_Float16)s3;
        hv[tt * 2 + 0] = p01;
        hv[tt * 2 + 1] = p23;
        m = fminf(m, fminf(fminf(s0, s1), fminf(s2, s3)));
    }
    m = fminf(m, __shfl_xor(m, 16));
    m = fminf(m, __shfl_xor(m, 32));
    if (lane < 16) mwv[wave][lane] = m;         // per-wave per-pixel half-min
    __syncthreads();

    // per-pixel global threshold: min over the two waves owning this pixel-tile
    const float thr = fminf(mwv[pt][lane & 15], mwv[pt + 4][lane & 15]) + W_SCR;

    // ---- pass 2: pure register scan, COLLECT candidates ----
    #pragma unroll
    for (int tt = 0; tt < 16; ++tt) {
        f16x2 p01 = hv[tt * 2 + 0];
        f16x2 p23 = hv[tt * 2 + 1];
        float s0 = (float)p01[0];
        float s1 = (float)p01[1];
        float s2 = (float)p23[0];
        float s3 = (float)p23[1];
        const int kb = (t0 + tt) * 16 + bg * 4;
        if (s0 < thr) { int s = atomicAdd(&lcnt, 1); if (s < LCAP) list[s] = bp * 512 + kb + 0; }
        if (s1 < thr) { int s = atomicAdd(&lcnt, 1); if (s < LCAP) list[s] = bp * 512 + kb + 1; }
        if (s2 < thr) { int s = atomicAdd(&lcnt, 1); if (s < LCAP) list[s] = bp * 512 + kb + 2; }
        if (s3 < thr) { int s = atomicAdd(&lcnt, 1); if (s < LCAP) list[s] = bp * 512 + kb + 3; }
    }
    __syncthreads();

    // ---- rescue: one candidate per lane, operands from LDS ----
    const int ncand = min(lcnt, LCAP);
    for (int i = tid; i < ncand; i += 512) {
        const int v = list[i];
        const int p = v >> 9;
        const int k = v & 511;
        const float* xp = &xf[p * XROW];
        const float* __restrict__ ep = emb + (k << 6);
        float a = 0.f;
        #pragma unroll
        for (int d = 0; d < D_EMB; ++d) a = fmaf(xp[d], ep[d], a);
        float X = t1s[p] + t2[k];
        float dnp = fmaf(-2.f, a, X);           // exact np-f32 dist
        unsigned long long key =
            ((unsigned long long)__float_as_uint(dnp) << 32) | (unsigned)k;
        atomicMin(&keys[p], key);
    }
    __syncthreads();

    // ---- epilogue: thread (p, oct=wave): 8 dims; loss partial ----
    float acc = 0.f;
    {
        const int p = tid & 63;
        const int n2 = blockIdx.x * 64 + p;
        const int kw = (int)(unsigned)(keys[p] & 0xFFFFFFFFull);
        float* __restrict__ qp = out_q + (n2 >> 10) * 65536 + (n2 & 1023);
        const float4* __restrict__ eq = (const float4*)(emb + (kw << 6) + wave * 8);
        #pragma unroll
        for (int j4 = 0; j4 < 2; ++j4) {
            float4 qv = eq[j4];
            const int d = wave * 8 + j4 * 4;
            float f0 = qv.x - xf[p * XROW + d + 0];
            float f1 = qv.y - xf[p * XROW + d + 1];
            float f2 = qv.z - xf[p * XROW + d + 2];
            float f3 = qv.w - xf[p * XROW + d + 3];
            acc = fmaf(f0, f0, acc);
            acc = fmaf(f1, f1, acc);
            acc = fmaf(f2, f2, acc);
            acc = fmaf(f3, f3, acc);
            qp[(d + 0) * 1024] = qv.x;
            qp[(d + 1) * 1024] = qv.y;
            qp[(d + 2) * 1024] = qv.z;
            qp[(d + 3) * 1024] = qv.w;
        }
        if (wave == 0) out_idx[n2] = (float)kw;
    }

    // block loss partial: per-wave shuffle reduce, then LDS across 8 waves
    #pragma unroll
    for (int off = 32; off > 0; off >>= 1) acc += __shfl_down(acc, off);
    if (lane == 0) red[wave] = acc;
    __syncthreads();
    if (tid == 0)
        partial[blockIdx.x] = ((red[0] + red[1]) + (red[2] + red[3]))
                            + ((red[4] + red[5]) + (red[6] + red[7]));
}

// ---------------- kernel 3: finalize loss over 1024 partials ----------------
__global__ __launch_bounds__(256) void vq_loss(const float* __restrict__ partial,
                                               float* __restrict__ loss) {
    const int t = threadIdx.x;
    float v = (partial[t] + partial[t + 256]) + (partial[t + 512] + partial[t + 768]);
    #pragma unroll
    for (int off = 32; off > 0; off >>= 1) v += __shfl_down(v, off);
    __shared__ float red[4];
    if ((t & 63) == 0) red[t >> 6] = v;
    __syncthreads();
    if (t == 0)
        loss[0] = 1.25f * ((red[0] + red[1]) + (red[2] + red[3])) / (float)Q_ELEMS;
}

extern "C" void kernel_launch(void* const* d_in, const int* in_sizes, int n_in,
                              void* d_out, int out_size, void* d_ws, size_t ws_size,
                              hipStream_t stream) {
    const float* x   = (const float*)d_in[0];   // [64,64,32,32] NCHW
    const float* emb = (const float*)d_in[1];   // [512,64]

    float* out_q    = (float*)d_out;                // [4194304]
    float* out_loss = (float*)d_out + Q_ELEMS;      // [1]
    float* out_idx  = (float*)d_out + Q_ELEMS + 1;  // [65536] as float

    float* t2      = (float*)d_ws;                  // 512
    float* t2s512  = t2 + K_EMB;                    // 512
    float* partial = t2s512 + K_EMB;                // 1024
    f16x8* embA    = (f16x8*)(partial + 1024);      // 4096 * 16B = 64KB

    vq_prep<<<16, 256, 0, stream>>>(emb, t2, t2s512, embA);
    vq_main<<<NBLK, 512, 0, stream>>>(x, emb, t2, t2s512, embA,
                                      out_q, out_idx, partial);
    vq_loss<<<1, 256, 0, stream>>>(partial, out_loss);
}

// Round 22
// 41.533 us; speedup vs baseline: 1.8350x; 1.0522x over previous
//
#include <hip/hip_runtime.h>
#include <float.h>

// VectorQuantizer on MI355X — MFMA f16 screen (register-held) + compacted np-f32
// rescue, x in LDS. R22 = R18's per-wave structure at HALF gang size:
// 256-thread blocks (4 waves), 32 pixels/block, 2048 blocks.
//
// R18/R21 (43.3/43.7us): occupancy counter pins at ~34% (≈11 waves/CU) though
// 4x8-wave blocks fit every resource -> block co-residency, not a pipe, is the
// suspect. R19/R20 regressions came from VGPR/LDS creep; here the per-wave
// world (fragments, hv[32], fmaf chains) is byte-identical to R18 so VGPR
// stays 64 and LDS halves to 11.2KB. Same thr merge (two waves per pixel-tile)
// -> identical candidate set -> bit-identical idx.
#pragma clang fp contract(off)

#define K_EMB   512
#define D_EMB   64
#define Q_ELEMS 4194304   // 64 * 64 * 32 * 32
#define PPB     32        // pixels per block
#define NBLK    2048      // 65536 / 32
#define W_SCR   0.5f      // rescue window, scaled (512x) — validated R13-R21
#define XROW    65        // xf row stride (odd -> bank-spread)
#define LCAP    512       // candidate list capacity (avg ~39/block)

typedef _Float16 f16x8 __attribute__((ext_vector_type(8)));
typedef _Float16 f16x2 __attribute__((ext_vector_type(2)));
typedef float    f32x4 __attribute__((ext_vector_type(4)));

// numpy pairwise_sum order for n=64 contiguous f32, summing PRE-ROUNDED squares.
__device__ __forceinline__ float np_sumsq64(const float* v) {
    float r[8];
    #pragma unroll
    for (int j = 0; j < 8; ++j) r[j] = v[j] * v[j];
    #pragma unroll
    for (int i = 8; i < 64; i += 8) {
        #pragma unroll
        for (int j = 0; j < 8; ++j) {
            float s = v[i + j] * v[i + j];
            r[j] = r[j] + s;
        }
    }
    return ((r[0] + r[1]) + (r[2] + r[3])) + ((r[4] + r[5]) + (r[6] + r[7]));
}

// ---------------- kernel 1: t2 (np-exact), 512-scaled t2, A-fragment table ----
// embA slot g=(t*2+s)*64+l: lane l's A-frag for code tile t, k-step s:
// code=t*16+(l&15), dims d = s*32+(l>>4)*8 .. +8, values u=512e (pow2-exact).
__global__ __launch_bounds__(256) void vq_prep(const float* __restrict__ emb,
                                               float* __restrict__ t2,
                                               float* __restrict__ t2s512,
                                               f16x8* __restrict__ embA) {
    const int g = blockIdx.x * 256 + threadIdx.x;
    if (g < K_EMB) {
        const float* ep = emb + (g << 6);
        float s = np_sumsq64(ep);
        t2[g]     = s;
        t2s512[g] = 512.0f * s;
    }
    if (g < 4096) {
        const int t = g >> 7;
        const int s = (g >> 6) & 1;
        const int l = g & 63;
        const int code  = t * 16 + (l & 15);
        const int dbase = s * 32 + ((l >> 4) << 3);
        const float* ep = emb + (code << 6) + dbase;
        f16x8 a;
        #pragma unroll
        for (int i = 0; i < 8; ++i) a[i] = (_Float16)(512.0f * ep[i]);
        embA[g] = a;
    }
}

// ---------------- kernel 2: main VQ (4 waves: pixel-tile x code-half) ---------
__global__ __launch_bounds__(256) void vq_main(const float* __restrict__ x,
                                               const float* __restrict__ emb,
                                               const float* __restrict__ t2,
                                               const float* __restrict__ t2s512,
                                               const f16x8* __restrict__ embA,
                                               float* __restrict__ out_q,
                                               float* __restrict__ out_idx,
                                               float* __restrict__ partial) {
    const int tid  = threadIdx.x;
    const int lane = tid & 63;
    const int wave = tid >> 6;                  // 0..3
    const int pt   = wave & 1;                  // pixel-tile (16 pixels)
    const int ch   = wave >> 1;                 // code-half (16 MFMA tiles)

    __shared__ float xf[PPB * XROW];            // f32 x-tile, staged ONCE (8.3 KB)
    __shared__ float t1s[PPB];                  // np-exact t1 per pixel
    __shared__ float mwv[4][16];                // per-(wave, pixel-in-tile) min
    __shared__ unsigned long long keys[PPB];    // (bits(dist)<<32)|k per pixel
    __shared__ int   list[LCAP];                // packed candidates p*512+k
    __shared__ int   lcnt;
    __shared__ float red[4];

    // ---- stage: thread (p = tid&31, oct = tid>>5) loads 8 dims, coalesced ----
    {
        const int p   = tid & 31;
        const int oct = tid >> 5;               // 0..7
        const int np_ = blockIdx.x * PPB + p;
        const float* __restrict__ xs = x + (np_ >> 10) * 65536 + (np_ & 1023);
        #pragma unroll
        for (int j = 0; j < 8; ++j) {
            const int d = oct * 8 + j;
            xf[p * XROW + d] = xs[d * 1024];
        }
        if (tid < PPB) keys[tid] = 0xFFFFFFFFFFFFFFFFull;
        if (tid == 0) lcnt = 0;
    }
    __syncthreads();

    // ---- t1 per pixel (np-exact, contiguous LDS row) ----
    if (tid < PPB) t1s[tid] = np_sumsq64(&xf[tid * XROW]);
    // (consumed by rescue, after the post-pass2 barrier)

    // ---- B-fragments for this wave's 16 pixels (RN f16 cvt from LDS f32) ----
    const int bp = 16 * pt + (lane & 15);       // pixel row (0..31)
    const int bg = lane >> 4;                   // code-slice group
    f16x8 b0, b1;
    #pragma unroll
    for (int i = 0; i < 8; ++i) {
        b0[i] = (_Float16)xf[bp * XROW + 0 * 32 + bg * 8 + i];
        b1[i] = (_Float16)xf[bp * XROW + 1 * 32 + bg * 8 + i];
    }

    const f32x4 czero = {0.f, 0.f, 0.f, 0.f};
    const float4* __restrict__ t2s4 = (const float4*)t2s512;
    const int t0 = ch * 16;                     // this wave's 16 code tiles

    // ---- pass 1: screen 256 codes; pack dists to f16 regs; track min ----
    f16x2 hv[32];                               // 64 screen values, packed
    float m = FLT_MAX;
    #pragma unroll
    for (int tt = 0; tt < 16; ++tt) {
        const int t = t0 + tt;
        f16x8 a0 = embA[(t * 2 + 0) * 64 + lane];
        f16x8 a1 = embA[(t * 2 + 1) * 64 + lane];
        f32x4 c = __builtin_amdgcn_mfma_f32_16x16x32_f16(a0, b0, czero, 0, 0, 0);
        c = __builtin_amdgcn_mfma_f32_16x16x32_f16(a1, b1, c, 0, 0, 0);
        float4 tv = t2s4[t * 4 + bg];
        float s0 = fmaf(-2.f, c[0], tv.x);
        float s1 = fmaf(-2.f, c[1], tv.y);
        float s2 = fmaf(-2.f, c[2], tv.z);
        float s3 = fmaf(-2.f, c[3], tv.w);
        f16x2 p01, p23;
        p01[0] = (_Float16)s0; p01[1] = (_Float16)s1;
        p23[0] = (_Float16)s2; p23[1] = (_Float16)s3;
        hv[tt * 2 + 0] = p01;
        hv[tt * 2 + 1] = p23;
        m = fminf(m, fminf(fminf(s0, s1), fminf(s2, s3)));
    }
    m = fminf(m, __shfl_xor(m, 16));
    m = fminf(m, __shfl_xor(m, 32));
    if (lane < 16) mwv[wave][lane] = m;         // per-wave per-pixel half-min
    __syncthreads();

    // per-pixel global threshold: min over the two waves owning this pixel-tile
    const float thr = fminf(mwv[pt][lane & 15], mwv[pt + 2][lane & 15]) + W_SCR;

    // ---- pass 2: pure register scan, COLLECT candidates ----
    #pragma unroll
    for (int tt = 0; tt < 16; ++tt) {
        f16x2 p01 = hv[tt * 2 + 0];
        f16x2 p23 = hv[tt * 2 + 1];
        float s0 = (float)p01[0];
        float s1 = (float)p01[1];
        float s2 = (float)p23[0];
        float s3 = (float)p23[1];
        const int kb = (t0 + tt) * 16 + bg * 4;
        if (s0 < thr) { int s = atomicAdd(&lcnt, 1); if (s < LCAP) list[s] = bp * 512 + kb + 0; }
        if (s1 < thr) { int s = atomicAdd(&lcnt, 1); if (s < LCAP) list[s] = bp * 512 + kb + 1; }
        if (s2 < thr) { int s = atomicAdd(&lcnt, 1); if (s < LCAP) list[s] = bp * 512 + kb + 2; }
        if (s3 < thr) { int s = atomicAdd(&lcnt, 1); if (s < LCAP) list[s] = bp * 512 + kb + 3; }
    }
    __syncthreads();

    // ---- rescue: one candidate per lane, operands from LDS ----
    const int ncand = min(lcnt, LCAP);
    for (int i = tid; i < ncand; i += 256) {
        const int v = list[i];
        const int p = v >> 9;
        const int k = v & 511;
        const float* xp = &xf[p * XROW];
        const float* __restrict__ ep = emb + (k << 6);
        float a = 0.f;
        #pragma unroll
        for (int d = 0; d < D_EMB; ++d) a = fmaf(xp[d], ep[d], a);
        float X = t1s[p] + t2[k];
        float dnp = fmaf(-2.f, a, X);           // exact np-f32 dist
        unsigned long long key =
            ((unsigned long long)__float_as_uint(dnp) << 32) | (unsigned)k;
        atomicMin(&keys[p], key);
    }
    __syncthreads();

    // ---- epilogue: thread (p = tid&31, q = tid>>5): 8 dims; loss partial ----
    float acc = 0.f;
    {
        const int p = tid & 31;
        const int q = tid >> 5;
        const int n2 = blockIdx.x * PPB + p;
        const int kw = (int)(unsigned)(keys[p] & 0xFFFFFFFFull);
        float* __restrict__ qp = out_q + (n2 >> 10) * 65536 + (n2 & 1023);
        const float4* __restrict__ eq = (const float4*)(emb + (kw << 6) + q * 8);
        #pragma unroll
        for (int j4 = 0; j4 < 2; ++j4) {
            float4 qv = eq[j4];
            const int d = q * 8 + j4 * 4;
            float f0 = qv.x - xf[p * XROW + d + 0];
            float f1 = qv.y - xf[p * XROW + d + 1];
            float f2 = qv.z - xf[p * XROW + d + 2];
            float f3 = qv.w - xf[p * XROW + d + 3];
            acc = fmaf(f0, f0, acc);
            acc = fmaf(f1, f1, acc);
            acc = fmaf(f2, f2, acc);
            acc = fmaf(f3, f3, acc);
            qp[(d + 0) * 1024] = qv.x;
            qp[(d + 1) * 1024] = qv.y;
            qp[(d + 2) * 1024] = qv.z;
            qp[(d + 3) * 1024] = qv.w;
        }
        if (q == 0) out_idx[n2] = (float)kw;
    }

    // block loss partial: per-wave shuffle reduce, then LDS across 4 waves
    #pragma unroll
    for (int off = 32; off > 0; off >>= 1) acc += __shfl_down(acc, off);
    if (lane == 0) red[wave] = acc;
    __syncthreads();
    if (tid == 0)
        partial[blockIdx.x] = (red[0] + red[1]) + (red[2] + red[3]);
}

// ---------------- kernel 3: finalize loss over 2048 partials ----------------
__global__ __launch_bounds__(256) void vq_loss(const float* __restrict__ partial,
                                               float* __restrict__ loss) {
    const int t = threadIdx.x;
    float v = ((partial[t] + partial[t + 256]) + (partial[t + 512] + partial[t + 768]))
            + ((partial[t + 1024] + partial[t + 1280])
               + (partial[t + 1536] + partial[t + 1792]));
    #pragma unroll
    for (int off = 32; off > 0; off >>= 1) v += __shfl_down(v, off);
    __shared__ float red[4];
    if ((t & 63) == 0) red[t >> 6] = v;
    __syncthreads();
    if (t == 0)
        loss[0] = 1.25f * ((red[0] + red[1]) + (red[2] + red[3])) / (float)Q_ELEMS;
}

extern "C" void kernel_launch(void* const* d_in, const int* in_sizes, int n_in,
                              void* d_out, int out_size, void* d_ws, size_t ws_size,
                              hipStream_t stream) {
    const float* x   = (const float*)d_in[0];   // [64,64,32,32] NCHW
    const float* emb = (const float*)d_in[1];   // [512,64]

    float* out_q    = (float*)d_out;                // [4194304]
    float* out_loss = (float*)d_out + Q_ELEMS;      // [1]
    float* out_idx  = (float*)d_out + Q_ELEMS + 1;  // [65536] as float

    float* t2      = (float*)d_ws;                  // 512
    float* t2s512  = t2 + K_EMB;                    // 512
    float* partial = t2s512 + K_EMB;                // 2048
    f16x8* embA    = (f16x8*)(partial + 2048);      // 12288B offset, 16B-aligned

    vq_prep<<<16, 256, 0, stream>>>(emb, t2, t2s512, embA);
    vq_main<<<NBLK, 256, 0, stream>>>(x, emb, t2, t2s512, embA,
                                      out_q, out_idx, partial);
    vq_loss<<<1, 256, 0, stream>>>(partial, out_loss);
}